// Round 13
// baseline (278.693 us; speedup 1.0000x reference)
//
#include <hip/hip_runtime.h>

#define D_DIM 1024
#define NROWS 8192

typedef float f32x4 __attribute__((ext_vector_type(4)));
typedef int   i32x4 __attribute__((ext_vector_type(4)));
typedef int   i32x8 __attribute__((ext_vector_type(8)));

typedef const __attribute__((address_space(1))) void* gaddr_t;
typedef __attribute__((address_space(3))) void* laddr_t;

__device__ __forceinline__ void load16_to_lds(const void* g, void* l) {
    __builtin_amdgcn_global_load_lds((gaddr_t)g, (laddr_t)l, 16, 0, 0);
}

// ---- kernel 1: fp32 row-normalize -> fp8 e4m3, one WAVE per row (no barriers).
// K is PERMUTED within each 128-element block (identically for A and B — dot
// products are K-permutation-invariant): orig k = 32s+8f+b (s=step 0..3,
// f=lane quarter 0..3, b=0..7) stored at byte (f + 4*(s>>1))*16 + (s&1)*8 + b.
// Lane l owns dest 16-B chunk at byte 16*l; 4 coalesced float4 loads/lane
// cover the row exactly once; ONE coalesced 16-B store/lane.
// Zeroes the encoded-max array and d_out (poisoned 0xAA every launch).
__global__ __launch_bounds__(256) void normalize_rows(const float* __restrict__ ex,
                                                      const float* __restrict__ ey,
                                                      unsigned char* __restrict__ Aq,
                                                      unsigned char* __restrict__ Bq,
                                                      int* __restrict__ maxenc,
                                                      float* __restrict__ out) {
    const int wave = threadIdx.x >> 6, lane = threadIdx.x & 63;
    const int r = blockIdx.x * 4 + wave;
    if (lane == 0) maxenc[r] = 0;   // 0 < int-encoding of any (cosine+2.0) > 0
    if (blockIdx.x == 0 && threadIdx.x < 2) out[threadIdx.x] = 0.0f;

    const float* src;
    unsigned char* dst;
    if (r < NROWS) { src = ex + (size_t)r * D_DIM;           dst = Aq + (size_t)r * D_DIM; }
    else           { src = ey + (size_t)(r - NROWS) * D_DIM; dst = Bq + (size_t)(r - NROWS) * D_DIM; }

    const int base4 = (lane >> 3) * 32 + ((lane >> 2) & 1) * 16 + (lane & 3) * 2; // float4 idx of base
    float4 va = ((const float4*)src)[base4];       // elements base .. base+3
    float4 vb = ((const float4*)src)[base4 + 1];   // base+4 .. base+7
    float4 vc = ((const float4*)src)[base4 + 8];   // base+32 .. base+35
    float4 vd = ((const float4*)src)[base4 + 9];   // base+36 .. base+39

    float ss = va.x * va.x + va.y * va.y + va.z * va.z + va.w * va.w
             + vb.x * vb.x + vb.y * vb.y + vb.z * vb.z + vb.w * vb.w
             + vc.x * vc.x + vc.y * vc.y + vc.z * vc.z + vc.w * vc.w
             + vd.x * vd.x + vd.y * vd.y + vd.z * vd.z + vd.w * vd.w;
    #pragma unroll
    for (int off = 32; off; off >>= 1) ss += __shfl_xor(ss, off, 64);
    float sc = 1.0f / fmaxf(sqrtf(ss), 1e-8f);

    i32x4 o;   // v_cvt_pk_fp8_f32: RNE, saturating; |x| <= ~0.3, no overflow
    int w;
    w = __builtin_amdgcn_cvt_pk_fp8_f32(va.x * sc, va.y * sc, 0, false);
    o[0] = __builtin_amdgcn_cvt_pk_fp8_f32(va.z * sc, va.w * sc, w, true);
    w = __builtin_amdgcn_cvt_pk_fp8_f32(vb.x * sc, vb.y * sc, 0, false);
    o[1] = __builtin_amdgcn_cvt_pk_fp8_f32(vb.z * sc, vb.w * sc, w, true);
    w = __builtin_amdgcn_cvt_pk_fp8_f32(vc.x * sc, vc.y * sc, 0, false);
    o[2] = __builtin_amdgcn_cvt_pk_fp8_f32(vc.z * sc, vc.w * sc, w, true);
    w = __builtin_amdgcn_cvt_pk_fp8_f32(vd.x * sc, vd.y * sc, 0, false);
    o[3] = __builtin_amdgcn_cvt_pk_fp8_f32(vd.z * sc, vd.w * sc, w, true);
    ((i32x4*)dst)[lane] = o;
}

// ---- kernel 2: 128x256-tile fp8 MFMA GEMM (C = A . B^T) with fused row/col max.
// MX-scaled v_mfma_scale_f32_16x16x128_f8f6f4, unit scales (E8M0 0x7F = 2^0)
// = exact fp8 math at ~2x non-scaled rate. BK=128, zero bank conflicts (16-B
// XOR swizzle + K-permutation), supertile block swizzle, #pragma unroll 1 +
// incremental pointers (kt-unroll balloons addressing -> spills, R11-R15).
// Ledger: 128^2@256thr = 85 us (R16/R18); 128x256@512thr single-buf = 82 us
// (R22, FETCH 135 MB, 2 blocks/CU, 16 waves/CU). Tile space exhausted:
// larger per-wave tiles need >=192 regs -> 2 waves/SIMD cliff; 3 blocks/CU
// needs <=85 regs/wave (impossible, acc=64). Residual vs floors (LDS 41,
// MFMA 29.5): per-iter stage->vmcnt(0)drain->compute serialization.
// R23: B-ONLY double-buffer + counted vmcnt, occupancy-preserving (R19's
// counted-vmcnt null was confounded by 3->2 blocks; here 16+2x32=80 KB and
// 2x80=160 KB exactly fits -> still 2 blocks/CU). Per iter t:
//   issue B(t+1)[4] -> Blds[(t+1)&1]   (flies across the whole compute)
//   s_waitcnt vmcnt(4)                 (drains exactly B(t)[4]+A(t)[2], the
//                                       6 oldest of 10 outstanding; FIFO)
//   s_barrier; compute(Alds, Blds[t&1]); s_barrier
//   issue A(t+1)[2] -> Alds            (readers done at the barrier; drains
//                                       at t+1's vmcnt before its barrier)
// In-flight writes during compute go ONLY to the other B buffer. sched_barrier
// fences stop ds_read hoisting across raw barriers (rule #18 hazard).
__global__ __launch_bounds__(512, 4) void gemm_max(const unsigned char* __restrict__ A,
                                                   const unsigned char* __restrict__ B,
                                                   int* __restrict__ rowmax,
                                                   int* __restrict__ colmax) {
    __shared__ __align__(16) unsigned char Alds[128 * 128];        // 16 KB
    __shared__ __align__(16) unsigned char Blds[2][256 * 128];     // 64 KB

    // grid 64(M) x 32(N) = 2048 blocks; 8x8 supertiles (bijective: 5+3+3 bits)
    const int bid = blockIdx.x;
    const int sgr = bid >> 6;
    const int bm  = ((sgr & 7) << 3) | ((bid >> 3) & 7);   // [0,64)
    const int bn  = ((sgr >> 3) << 3) | (bid & 7);         // [0,32)
    const int rowb = bm * 128;
    const int colb = bn * 256;

    const int t    = threadIdx.x;
    const int lane = t & 63;
    const int wave = t >> 6;              // [0,8)
    const int wm = (wave & 1) * 64;       // wave row offset within tile
    const int wn = (wave >> 1) * 64;      // wave col offset within tile [0,256)
    const int fr = lane & 15;             // fragment row/col index
    const int fq = lane >> 4;             // quarter: k-chunk index
    const int pos1 = (fq ^ (fr & 7)) * 16;   // swizzled LDS pos of chunk fq

    // staging: thread t stages rows srow + 64*i, pos t&7 (lane-linear dest:
    // wave*1024 + lane*16 + i*8192); source col swizzle invariant under row+64
    const int srow = t >> 3;                         // [0,64)
    const int scol = ((t ^ (t >> 3)) & 7) * 16;

    const unsigned char* ag = A + (size_t)(rowb + srow) * D_DIM + scol;
    const unsigned char* bg = B + (size_t)(colb + srow) * D_DIM + scol;

    f32x4 acc[4][4] = {};

    // prologue: B(0) then A(0) (issue order matters for vmcnt FIFO accounting)
    #pragma unroll
    for (int i = 0; i < 4; ++i)
        load16_to_lds(bg + (size_t)i * 64 * D_DIM,
                      (char*)Blds[0] + wave * 1024 + i * 8192);
    bg += 128;
    #pragma unroll
    for (int i = 0; i < 2; ++i)
        load16_to_lds(ag + (size_t)i * 64 * D_DIM,
                      (char*)Alds + wave * 1024 + i * 8192);
    ag += 128;

    #pragma unroll 1
    for (int tt = 0; tt < 8; ++tt) {
        if (tt < 7) {   // prefetch B(tt+1); its buffer's readers finished at
                        // the end-barrier of iter tt-1
            char* Bn = (char*)Blds[(tt + 1) & 1];
            #pragma unroll
            for (int i = 0; i < 4; ++i)
                load16_to_lds(bg + (size_t)i * 64 * D_DIM, Bn + wave * 1024 + i * 8192);
            bg += 128;
            // outstanding: B(tt)4 + A(tt)2 + B(tt+1)4 = 10; drain oldest 6
            asm volatile("s_waitcnt vmcnt(4)" ::: "memory");
        } else {
            asm volatile("s_waitcnt vmcnt(0)" ::: "memory");
        }
        __builtin_amdgcn_s_barrier();          // tiles tt fully visible
        __builtin_amdgcn_sched_barrier(0);

        const unsigned char* Bc = (const unsigned char*)Blds[tt & 1];
        // A fragments: 4 rows x 32 B (chunk fq then chunk fq^4, same order as B)
        i32x8 af[4];
        #pragma unroll
        for (int i = 0; i < 4; ++i) {
            i32x4 lo = *(const i32x4*)(Alds + (wm + i * 16 + fr) * 128 + pos1);
            i32x4 hi = *(const i32x4*)(Alds + (wm + i * 16 + fr) * 128 + (pos1 ^ 64));
            af[i] = __builtin_shufflevector(lo, hi, 0, 1, 2, 3, 4, 5, 6, 7);
        }
        #pragma unroll
        for (int j = 0; j < 4; ++j) {
            i32x4 lo = *(const i32x4*)(Bc + (wn + j * 16 + fr) * 128 + pos1);
            i32x4 hi = *(const i32x4*)(Bc + (wn + j * 16 + fr) * 128 + (pos1 ^ 64));
            i32x8 bf = __builtin_shufflevector(lo, hi, 0, 1, 2, 3, 4, 5, 6, 7);
            #pragma unroll
            for (int i = 0; i < 4; ++i)
                acc[i][j] = __builtin_amdgcn_mfma_scale_f32_16x16x128_f8f6f4(
                    af[i], bf, acc[i][j],
                    0, 0,                 // cbsz=0 (A: fp8 e4m3), blgp=0 (B: fp8 e4m3)
                    0, 0x7F7F7F7F,        // scale_a: every block exponent = 2^0
                    0, 0x7F7F7F7F);       // scale_b: every block exponent = 2^0
        }

        __builtin_amdgcn_sched_barrier(0);
        __builtin_amdgcn_s_barrier();          // all reads of tile tt done
        if (tt < 7) {   // stage A(tt+1) into the (now idle) single A buffer
            #pragma unroll
            for (int i = 0; i < 2; ++i)
                load16_to_lds(ag + (size_t)i * 64 * D_DIM,
                              (char*)Alds + wave * 1024 + i * 8192);
            ag += 128;
        }
    }

    // ---- epilogue: fused max reductions.
    // C/D layout (shape-determined, m89-verified): col = lane&15, row = fq*4 + reg.
    const float SH = 2.0f;   // cosine >= -1 -> v+2 > 0 -> int-ordered float bits

    #pragma unroll
    for (int i = 0; i < 4; ++i) {
        #pragma unroll
        for (int r = 0; r < 4; ++r) {
            float m = fmaxf(fmaxf(acc[i][0][r], acc[i][1][r]),
                            fmaxf(acc[i][2][r], acc[i][3][r]));
            m = fmaxf(m, __shfl_xor(m, 1, 64));   // reduce over the 16 lanes sharing fq
            m = fmaxf(m, __shfl_xor(m, 2, 64));
            m = fmaxf(m, __shfl_xor(m, 4, 64));
            m = fmaxf(m, __shfl_xor(m, 8, 64));
            if (fr == 0) {
                int row = rowb + wm + i * 16 + fq * 4 + r;
                atomicMax(&rowmax[row], __float_as_int(m + SH));
            }
        }
    }
    #pragma unroll
    for (int j = 0; j < 4; ++j) {
        float m = -1e30f;
        #pragma unroll
        for (int i = 0; i < 4; ++i)
            #pragma unroll
            for (int r = 0; r < 4; ++r)
                m = fmaxf(m, acc[i][j][r]);
        m = fmaxf(m, __shfl_xor(m, 16, 64));      // reduce over the 4 quarters
        m = fmaxf(m, __shfl_xor(m, 32, 64));
        if (fq == 0) {
            int col = colb + wn + j * 16 + fr;
            atomicMax(&colmax[col], __float_as_int(m + SH));
        }
    }
}

// ---- kernel 3: decode maxes, log-prob, partial-sum, atomicAdd into out.
// 64 blocks x 256 threads over the contiguous [rowmax | colmax] array; each
// block's 256 entries lie entirely in one half. out zeroed by normalize_rows.
__global__ __launch_bounds__(256) void finalize(const int* __restrict__ maxenc,
                                                float* __restrict__ out) {
    int idx = blockIdx.x * 256 + threadIdx.x;
    float v = __int_as_float(maxenc[idx]) - 2.0f;
    float z = (v - 1.0f) * (1.0f / 0.3f);
    float s = -0.5f * z * z + 0.2850342711212634f;   // -(log(0.3)+0.5*log(2*pi))
    #pragma unroll
    for (int off = 32; off; off >>= 1) s += __shfl_xor(s, off, 64);
    __shared__ float wsum[4];
    if ((threadIdx.x & 63) == 0) wsum[threadIdx.x >> 6] = s;
    __syncthreads();
    if (threadIdx.x == 0)
        atomicAdd(&out[idx >= NROWS ? 1 : 0], wsum[0] + wsum[1] + wsum[2] + wsum[3]);
}

extern "C" void kernel_launch(void* const* d_in, const int* in_sizes, int n_in,
                              void* d_out, int out_size, void* d_ws, size_t ws_size,
                              hipStream_t stream) {
    const float* ex = (const float*)d_in[0];
    const float* ey = (const float*)d_in[1];
    float* out = (float*)d_out;

    char* ws = (char*)d_ws;
    unsigned char* Aq = (unsigned char*)ws;                                   // 8 MB
    unsigned char* Bq = (unsigned char*)(ws + (size_t)NROWS * D_DIM);         // 8 MB
    int* rowmax = (int*)(ws + (size_t)2 * NROWS * D_DIM);                     // 32 KB
    int* colmax = rowmax + NROWS;                                             // 32 KB

    normalize_rows<<<(2 * NROWS) / 4, 256, 0, stream>>>(ex, ey, Aq, Bq, rowmax, out);
    gemm_max<<<64 * 32, 512, 0, stream>>>(Aq, Bq, rowmax, colmax);
    finalize<<<64, 256, 0, stream>>>(rowmax, out);
}

// Round 14
// 168.018 us; speedup vs baseline: 1.6587x; 1.6587x over previous
//
#include <hip/hip_runtime.h>

#define D_DIM 1024
#define NROWS 8192

typedef float f32x4 __attribute__((ext_vector_type(4)));
typedef int   i32x4 __attribute__((ext_vector_type(4)));
typedef int   i32x8 __attribute__((ext_vector_type(8)));

typedef const __attribute__((address_space(1))) void* gaddr_t;
typedef __attribute__((address_space(3))) void* laddr_t;

__device__ __forceinline__ void load16_to_lds(const void* g, void* l) {
    __builtin_amdgcn_global_load_lds((gaddr_t)g, (laddr_t)l, 16, 0, 0);
}

// ---- kernel 1: fp32 row-normalize -> fp8 e4m3, one WAVE per row (no barriers).
// K is PERMUTED within each 128-element block (identically for A and B — dot
// products are K-permutation-invariant): orig k = 32s+8f+b (s=step 0..3,
// f=lane quarter 0..3, b=0..7) stored at byte (f + 4*(s>>1))*16 + (s&1)*8 + b.
// Lane l owns dest 16-B chunk at byte 16*l; 4 coalesced float4 loads/lane
// cover the row exactly once; ONE coalesced 16-B store/lane.
// Zeroes the encoded-max array and d_out (poisoned 0xAA every launch).
__global__ __launch_bounds__(256) void normalize_rows(const float* __restrict__ ex,
                                                      const float* __restrict__ ey,
                                                      unsigned char* __restrict__ Aq,
                                                      unsigned char* __restrict__ Bq,
                                                      int* __restrict__ maxenc,
                                                      float* __restrict__ out) {
    const int wave = threadIdx.x >> 6, lane = threadIdx.x & 63;
    const int r = blockIdx.x * 4 + wave;
    if (lane == 0) maxenc[r] = 0;   // 0 < int-encoding of any (cosine+2.0) > 0
    if (blockIdx.x == 0 && threadIdx.x < 2) out[threadIdx.x] = 0.0f;

    const float* src;
    unsigned char* dst;
    if (r < NROWS) { src = ex + (size_t)r * D_DIM;           dst = Aq + (size_t)r * D_DIM; }
    else           { src = ey + (size_t)(r - NROWS) * D_DIM; dst = Bq + (size_t)(r - NROWS) * D_DIM; }

    const int base4 = (lane >> 3) * 32 + ((lane >> 2) & 1) * 16 + (lane & 3) * 2; // float4 idx of base
    float4 va = ((const float4*)src)[base4];       // elements base .. base+3
    float4 vb = ((const float4*)src)[base4 + 1];   // base+4 .. base+7
    float4 vc = ((const float4*)src)[base4 + 8];   // base+32 .. base+35
    float4 vd = ((const float4*)src)[base4 + 9];   // base+36 .. base+39

    float ss = va.x * va.x + va.y * va.y + va.z * va.z + va.w * va.w
             + vb.x * vb.x + vb.y * vb.y + vb.z * vb.z + vb.w * vb.w
             + vc.x * vc.x + vc.y * vc.y + vc.z * vc.z + vc.w * vc.w
             + vd.x * vd.x + vd.y * vd.y + vd.z * vd.z + vd.w * vd.w;
    #pragma unroll
    for (int off = 32; off; off >>= 1) ss += __shfl_xor(ss, off, 64);
    float sc = 1.0f / fmaxf(sqrtf(ss), 1e-8f);

    i32x4 o;   // v_cvt_pk_fp8_f32: RNE, saturating; |x| <= ~0.3, no overflow
    int w;
    w = __builtin_amdgcn_cvt_pk_fp8_f32(va.x * sc, va.y * sc, 0, false);
    o[0] = __builtin_amdgcn_cvt_pk_fp8_f32(va.z * sc, va.w * sc, w, true);
    w = __builtin_amdgcn_cvt_pk_fp8_f32(vb.x * sc, vb.y * sc, 0, false);
    o[1] = __builtin_amdgcn_cvt_pk_fp8_f32(vb.z * sc, vb.w * sc, w, true);
    w = __builtin_amdgcn_cvt_pk_fp8_f32(vc.x * sc, vc.y * sc, 0, false);
    o[2] = __builtin_amdgcn_cvt_pk_fp8_f32(vc.z * sc, vc.w * sc, w, true);
    w = __builtin_amdgcn_cvt_pk_fp8_f32(vd.x * sc, vd.y * sc, 0, false);
    o[3] = __builtin_amdgcn_cvt_pk_fp8_f32(vd.z * sc, vd.w * sc, w, true);
    ((i32x4*)dst)[lane] = o;
}

// ---- kernel 2: 128x256-tile fp8 MFMA GEMM (C = A . B^T) with fused row/col max.
// MX-scaled v_mfma_scale_f32_16x16x128_f8f6f4, unit scales (E8M0 0x7F = 2^0)
// = exact fp8 math at ~2x non-scaled rate. BK=128, single LDS buffer (16 KB A
// + 32 KB B), 2-barrier K-loop, zero bank conflicts (16-B XOR swizzle +
// K-permutation), XCD-aware supertile block swizzle, #pragma unroll 1 +
// incremental pointers.
// FINAL structure ledger (this frame, acc=64 AGPR + ~64 arch per wave):
//   128^2@256thr single-buf (R16/R18):        85 us, 3 blocks/CU
//   any dbuf at -1 resident block (R17/R19):  112-114 us (occupancy loss wins)
//   128x256@512thr single-buf (R22, THIS):    82 us, 2 blocks/CU 16 waves/CU,
//                                             FETCH 135 MB, no spill
//   B-only dbuf + counted vmcnt (R23):        197 us — schedule stretching
//     (prefetch-before-compute + sched_barrier fences) pushed live ranges
//     past the 64-arch half -> 510 MB scratch writes (R11-signature spill)
//   fused finalize (R21): +18 us/dispatch, tail unchanged -> unfused
// Conclusion: the 2-phase frame at acc=64 has NO register headroom for any
// software pipelining; 82 us is its TLP plateau (floors: LDS 41, MFMA 29.5).
// Staging map (lane-linear dest, required by global_load_lds): thread t,
// iter i: dest = wave*1024 + lane*16 + i*8192 = (srow + 64*i)*128 + pos*16,
// srow = t>>3, pos = t&7; source col ((t^(t>>3))&7)*16 invariant under row+64.
__global__ __launch_bounds__(512, 4) void gemm_max(const unsigned char* __restrict__ A,
                                                   const unsigned char* __restrict__ B,
                                                   int* __restrict__ rowmax,
                                                   int* __restrict__ colmax) {
    __shared__ __align__(16) unsigned char Alds[128 * 128];   // 16 KB
    __shared__ __align__(16) unsigned char Blds[256 * 128];   // 32 KB

    // grid 64(M) x 32(N) = 2048 blocks; 8x8 supertiles (bijective: 5+3+3 bits)
    const int bid = blockIdx.x;
    const int sgr = bid >> 6;
    const int bm  = ((sgr & 7) << 3) | ((bid >> 3) & 7);   // [0,64)
    const int bn  = ((sgr >> 3) << 3) | (bid & 7);         // [0,32)
    const int rowb = bm * 128;
    const int colb = bn * 256;

    const int t    = threadIdx.x;
    const int lane = t & 63;
    const int wave = t >> 6;              // [0,8)
    const int wm = (wave & 1) * 64;       // wave row offset within tile
    const int wn = (wave >> 1) * 64;      // wave col offset within tile [0,256)
    const int fr = lane & 15;             // fragment row/col index
    const int fq = lane >> 4;             // quarter: k-chunk index
    const int pos1 = (fq ^ (fr & 7)) * 16;   // swizzled LDS pos of chunk fq

    // staging: thread t stages rows srow, srow+64(,+128,+192 for B), pos t&7
    const int srow = t >> 3;                         // [0,64)
    const int scol = ((t ^ (t >> 3)) & 7) * 16;

    const unsigned char* ag = A + (size_t)(rowb + srow) * D_DIM + scol;
    const unsigned char* bg = B + (size_t)(colb + srow) * D_DIM + scol;

    f32x4 acc[4][4] = {};

    #pragma unroll 1
    for (int kt = 0; kt < D_DIM; kt += 128) {
        #pragma unroll
        for (int i = 0; i < 2; ++i)       // A: 128 rows
            load16_to_lds(ag + (size_t)i * 64 * D_DIM,
                          (char*)Alds + wave * 1024 + i * 8192);
        #pragma unroll
        for (int i = 0; i < 4; ++i)       // B: 256 rows
            load16_to_lds(bg + (size_t)i * 64 * D_DIM,
                          (char*)Blds + wave * 1024 + i * 8192);
        ag += 128;
        bg += 128;
        __syncthreads();

        // A fragments: 4 rows x 32 B (chunk fq then chunk fq^4, same order as B)
        i32x8 af[4];
        #pragma unroll
        for (int i = 0; i < 4; ++i) {
            i32x4 lo = *(const i32x4*)(Alds + (wm + i * 16 + fr) * 128 + pos1);
            i32x4 hi = *(const i32x4*)(Alds + (wm + i * 16 + fr) * 128 + (pos1 ^ 64));
            af[i] = __builtin_shufflevector(lo, hi, 0, 1, 2, 3, 4, 5, 6, 7);
        }
        #pragma unroll
        for (int j = 0; j < 4; ++j) {
            i32x4 lo = *(const i32x4*)(Blds + (wn + j * 16 + fr) * 128 + pos1);
            i32x4 hi = *(const i32x4*)(Blds + (wn + j * 16 + fr) * 128 + (pos1 ^ 64));
            i32x8 bf = __builtin_shufflevector(lo, hi, 0, 1, 2, 3, 4, 5, 6, 7);
            #pragma unroll
            for (int i = 0; i < 4; ++i)
                acc[i][j] = __builtin_amdgcn_mfma_scale_f32_16x16x128_f8f6f4(
                    af[i], bf, acc[i][j],
                    0, 0,                 // cbsz=0 (A: fp8 e4m3), blgp=0 (B: fp8 e4m3)
                    0, 0x7F7F7F7F,        // scale_a: every block exponent = 2^0
                    0, 0x7F7F7F7F);       // scale_b: every block exponent = 2^0
        }
        __syncthreads();
    }

    // ---- epilogue: fused max reductions.
    // C/D layout (shape-determined, m89-verified): col = lane&15, row = fq*4 + reg.
    const float SH = 2.0f;   // cosine >= -1 -> v+2 > 0 -> int-ordered float bits

    #pragma unroll
    for (int i = 0; i < 4; ++i) {
        #pragma unroll
        for (int r = 0; r < 4; ++r) {
            float m = fmaxf(fmaxf(acc[i][0][r], acc[i][1][r]),
                            fmaxf(acc[i][2][r], acc[i][3][r]));
            m = fmaxf(m, __shfl_xor(m, 1, 64));   // reduce over the 16 lanes sharing fq
            m = fmaxf(m, __shfl_xor(m, 2, 64));
            m = fmaxf(m, __shfl_xor(m, 4, 64));
            m = fmaxf(m, __shfl_xor(m, 8, 64));
            if (fr == 0) {
                int row = rowb + wm + i * 16 + fq * 4 + r;
                atomicMax(&rowmax[row], __float_as_int(m + SH));
            }
        }
    }
    #pragma unroll
    for (int j = 0; j < 4; ++j) {
        float m = -1e30f;
        #pragma unroll
        for (int i = 0; i < 4; ++i)
            #pragma unroll
            for (int r = 0; r < 4; ++r)
                m = fmaxf(m, acc[i][j][r]);
        m = fmaxf(m, __shfl_xor(m, 16, 64));      // reduce over the 4 quarters
        m = fmaxf(m, __shfl_xor(m, 32, 64));
        if (fq == 0) {
            int col = colb + wn + j * 16 + fr;
            atomicMax(&colmax[col], __float_as_int(m + SH));
        }
    }
}

// ---- kernel 3: decode maxes, log-prob, partial-sum, atomicAdd into out.
// 64 blocks x 256 threads over the contiguous [rowmax | colmax] array; each
// block's 256 entries lie entirely in one half. out zeroed by normalize_rows.
__global__ __launch_bounds__(256) void finalize(const int* __restrict__ maxenc,
                                                float* __restrict__ out) {
    int idx = blockIdx.x * 256 + threadIdx.x;
    float v = __int_as_float(maxenc[idx]) - 2.0f;
    float z = (v - 1.0f) * (1.0f / 0.3f);
    float s = -0.5f * z * z + 0.2850342711212634f;   // -(log(0.3)+0.5*log(2*pi))
    #pragma unroll
    for (int off = 32; off; off >>= 1) s += __shfl_xor(s, off, 64);
    __shared__ float wsum[4];
    if ((threadIdx.x & 63) == 0) wsum[threadIdx.x >> 6] = s;
    __syncthreads();
    if (threadIdx.x == 0)
        atomicAdd(&out[idx >= NROWS ? 1 : 0], wsum[0] + wsum[1] + wsum[2] + wsum[3]);
}

extern "C" void kernel_launch(void* const* d_in, const int* in_sizes, int n_in,
                              void* d_out, int out_size, void* d_ws, size_t ws_size,
                              hipStream_t stream) {
    const float* ex = (const float*)d_in[0];
    const float* ey = (const float*)d_in[1];
    float* out = (float*)d_out;

    char* ws = (char*)d_ws;
    unsigned char* Aq = (unsigned char*)ws;                                   // 8 MB
    unsigned char* Bq = (unsigned char*)(ws + (size_t)NROWS * D_DIM);         // 8 MB
    int* rowmax = (int*)(ws + (size_t)2 * NROWS * D_DIM);                     // 32 KB
    int* colmax = rowmax + NROWS;                                             // 32 KB

    normalize_rows<<<(2 * NROWS) / 4, 256, 0, stream>>>(ex, ey, Aq, Bq, rowmax, out);
    gemm_max<<<64 * 32, 512, 0, stream>>>(Aq, Bq, rowmax, colmax);
    finalize<<<64, 256, 0, stream>>>(rowmax, out);
}